// Round 2
// baseline (90.585 us; speedup 1.0000x reference)
//
#include <hip/hip_runtime.h>

// Problem constants
#define TA_ELEMS 52488          // 9^4 * 8 per aggregator (original T layout)
#define TT_ISTRIDE 672          // transposed: per-i stride = 8 r * 84 padded j
#define TT_ELEMS (4 * 81 * 672) // 217728 floats

// Transpose T[a][q0][q1][q2][q3][r] (flat a*52488 + i*648 + j*8 + r, i=q0*9+q1, j=q2*9+q3)
//        -> Tt[a][i][r][84]  where the 84 j-columns are THREE 28-wide thirds:
//        col = jt*28 + (j - jt*27), jt = j/27; slot 27 of each third is zero pad.
//        (28-stride keeps every third 16B-aligned for float4 reads in phase B.)
__global__ void t_transpose(const float* __restrict__ T, float* __restrict__ Tt) {
    int idx = blockIdx.x * 256 + threadIdx.x;
    if (idx >= TT_ELEMS) return;
    int col  = idx % 84;
    int t1   = idx / 84;
    int r    = t1 & 7;
    int rest = t1 >> 3;  // a*81 + i
    int jt   = col / 28;
    int kk   = col - jt * 28;      // 0..27; 27 = pad
    Tt[idx] = (kk < 27) ? T[rest * 648 + (jt * 27 + kk) * 8 + r] : 0.0f;
}

// One block: 512 threads = 8 waves, handles (64 batches) x (one aggregator a).
// grid = (8192/64) * 4 = 512 blocks -> exactly 2 blocks/CU (69.6 KB LDS each).
__global__ __launch_bounds__(512, 4) void hosvd_fused(
    const float* __restrict__ nh,   // [8192][4][256]
    const float* __restrict__ U,    // [4][4][256][8]
    const float* __restrict__ bi,   // [4][4][1][8]
    const float* __restrict__ Uo,   // [4][8][256]
    const float* __restrict__ bo,   // [4][1][256]
    const float* __restrict__ Tt,   // transposed T in ws
    float* __restrict__ out) {      // [8192][1024]
    __shared__ float u_lds[4 * 256 * 8];   // 32 KB: U[c][a=blk][h][r]
    __shared__ float h_lds[64][40];        // 10 KB: per-batch augmented h (4c x 9q), pad to 40
    __shared__ float red[8][64][9];        // 18 KB: per-wave partial ris, pad r-dim to 9
    __shared__ float uo_lds[8 * 256];      // 8 KB:  U_out[a][r][h]

    const int t    = threadIdx.x;
    const int lane = t & 63;
    const int widr = t >> 6;
    const int a    = blockIdx.x & 3;
    const int b0   = (blockIdx.x >> 2) << 6;

    // ---- stage U[., a, ., .] and Uo[a] into LDS (coalesced)
    for (int idx = t; idx < 8192; idx += 512) {
        int c   = idx >> 11;
        int rem = idx & 2047;              // h*8 + r
        u_lds[idx] = U[((c * 4 + a) << 11) + rem];
    }
    for (int idx = t; idx < 2048; idx += 512)
        uo_lds[idx] = Uo[(a << 11) + idx];
    __syncthreads();

    // ---- phase X: x[b][c][r] = nh[b,c,:] . U[c,a,:,r] + bi[c,a,r]  -> h_lds
    {
        const int c  = widr >> 1;
        const int r0 = (widr & 1) << 2;
        const float* nhp   = nh + (size_t)(b0 + lane) * 1024 + (size_t)c * 256;
        const float* ubase = u_lds + (c << 11) + r0;
        float4 acc = make_float4(0.f, 0.f, 0.f, 0.f);
        #pragma unroll 4
        for (int h = 0; h < 256; h += 4) {
            float4 v  = *(const float4*)(nhp + h);
            float4 u0 = *(const float4*)(ubase + ((h + 0) << 3));
            float4 u1 = *(const float4*)(ubase + ((h + 1) << 3));
            float4 u2 = *(const float4*)(ubase + ((h + 2) << 3));
            float4 u3 = *(const float4*)(ubase + ((h + 3) << 3));
            acc.x = fmaf(v.x, u0.x, acc.x); acc.y = fmaf(v.x, u0.y, acc.y);
            acc.z = fmaf(v.x, u0.z, acc.z); acc.w = fmaf(v.x, u0.w, acc.w);
            acc.x = fmaf(v.y, u1.x, acc.x); acc.y = fmaf(v.y, u1.y, acc.y);
            acc.z = fmaf(v.y, u1.z, acc.z); acc.w = fmaf(v.y, u1.w, acc.w);
            acc.x = fmaf(v.z, u2.x, acc.x); acc.y = fmaf(v.z, u2.y, acc.y);
            acc.z = fmaf(v.z, u2.z, acc.z); acc.w = fmaf(v.z, u2.w, acc.w);
            acc.x = fmaf(v.w, u3.x, acc.x); acc.y = fmaf(v.w, u3.y, acc.y);
            acc.z = fmaf(v.w, u3.z, acc.z); acc.w = fmaf(v.w, u3.w, acc.w);
        }
        const float4 bb = *(const float4*)&bi[((c * 4 + a) << 3) + r0];
        h_lds[lane][c * 9 + r0 + 0] = acc.x + bb.x;
        h_lds[lane][c * 9 + r0 + 1] = acc.y + bb.y;
        h_lds[lane][c * 9 + r0 + 2] = acc.z + bb.z;
        h_lds[lane][c * 9 + r0 + 3] = acc.w + bb.w;
        if (r0) h_lds[lane][c * 9 + 8] = 1.0f;   // augmented 1
    }
    // zero this thread's partial slots
    #pragma unroll
    for (int r = 0; r < 8; ++r) red[widr][lane][r] = 0.0f;
    __syncthreads();

    // ---- phase B: ris[r] = sum_{i,j} h0[q0]h1[q1] h2[q2]h3[q3] T[i,j,r]
    // 24 sweeps of 27 j's (one r each); 8 waves x 3 sweeps. T streams via SGPR (wave-uniform).
    {
        float h1v[9], h3v[9];
        #pragma unroll
        for (int q = 0; q < 9; ++q) {
            h1v[q] = h_lds[lane][9 + q];
            h3v[q] = h_lds[lane][27 + q];
        }
        const int wid = __builtin_amdgcn_readfirstlane(widr);
        const float* Tw = Tt + (size_t)(a * 81) * TT_ISTRIDE;
        #pragma unroll 1
        for (int ss = 0; ss < 3; ++ss) {
            const int sg = wid * 3 + ss;     // global sweep id 0..23
            const int r  = sg & 7;
            const int jt = sg >> 3;          // j-third 0..2
            const float* tb = Tw + r * 84 + jt * 28;   // 28-stride thirds (see transpose)
            float z[27];
            #pragma unroll
            for (int k = 0; k < 27; ++k) z[k] = 0.0f;
            #pragma unroll 1
            for (int q0 = 0; q0 < 9; ++q0) {
                const float h0v = h_lds[lane][q0];
                #pragma unroll
                for (int q1 = 0; q1 < 9; ++q1) {
                    const float* tp = tb + (q0 * 9 + q1) * TT_ISTRIDE;
                    float ta[28];
                    #pragma unroll
                    for (int m = 0; m < 7; ++m)
                        *(float4*)(ta + 4 * m) = *(const float4*)(tp + 4 * m);
                    const float w = h0v * h1v[q1];
                    #pragma unroll
                    for (int k = 0; k < 27; ++k) z[k] = fmaf(w, ta[k], z[k]);
                }
            }
            // fold j-dimension: j = jt*27 + k, q2 = 3*jt + k/9, q3 = k%9
            const int h2base = 18 + jt * 3;
            const float h2a = h_lds[lane][h2base + 0];
            const float h2b = h_lds[lane][h2base + 1];
            const float h2c = h_lds[lane][h2base + 2];
            float d0 = 0.f, d1 = 0.f, d2 = 0.f;
            #pragma unroll
            for (int k = 0; k < 9; ++k) {
                d0 = fmaf(h3v[k], z[k],      d0);
                d1 = fmaf(h3v[k], z[9 + k],  d1);
                d2 = fmaf(h3v[k], z[18 + k], d2);
            }
            red[wid][lane][r] = fmaf(h2a, d0, fmaf(h2b, d1, h2c * d2));
        }
    }
    __syncthreads();

    // ---- reduce 8 wave-partials -> ris, stored into h_lds[b][r]
    {
        const int b = t >> 3, r = t & 7;
        float s = 0.f;
        #pragma unroll
        for (int w = 0; w < 8; ++w) s += red[w][b][r];
        h_lds[b][r] = s;
    }
    __syncthreads();

    // ---- phase C: out[b, a*256+h] = sum_r ris[b][r]*Uo[a][r][h] + bo[a][h]
    {
        const int h  = t & 255;
        const int bh = t >> 8;   // 0..1
        const float bov = bo[(a << 8) + h];
        const float u0 = uo_lds[h],            u1 = uo_lds[256 + h];
        const float u2 = uo_lds[512 + h],      u3 = uo_lds[768 + h];
        const float u4 = uo_lds[1024 + h],     u5 = uo_lds[1280 + h];
        const float u6 = uo_lds[1536 + h],     u7 = uo_lds[1792 + h];
        float* op = out + (size_t)(b0 + (bh << 5)) * 1024 + (a << 8) + h;
        #pragma unroll 4
        for (int bb = 0; bb < 32; ++bb) {
            const float* rp = h_lds[(bh << 5) + bb];
            float v = bov;
            v = fmaf(rp[0], u0, v); v = fmaf(rp[1], u1, v);
            v = fmaf(rp[2], u2, v); v = fmaf(rp[3], u3, v);
            v = fmaf(rp[4], u4, v); v = fmaf(rp[5], u5, v);
            v = fmaf(rp[6], u6, v); v = fmaf(rp[7], u7, v);
            op[(size_t)bb * 1024] = v;
        }
    }
}

extern "C" void kernel_launch(void* const* d_in, const int* in_sizes, int n_in,
                              void* d_out, int out_size, void* d_ws, size_t ws_size,
                              hipStream_t stream) {
    (void)in_sizes; (void)n_in; (void)out_size; (void)ws_size;
    const float* nh = (const float*)d_in[0];
    const float* U  = (const float*)d_in[1];
    const float* bi = (const float*)d_in[2];
    const float* Uo = (const float*)d_in[3];
    const float* bo = (const float*)d_in[4];
    const float* T  = (const float*)d_in[5];
    float* outp = (float*)d_out;
    float* Tt   = (float*)d_ws;   // needs 217728*4 = 870,912 bytes

    t_transpose<<<(TT_ELEMS + 255) / 256, 256, 0, stream>>>(T, Tt);
    hosvd_fused<<<512, 512, 0, stream>>>(nh, U, bi, Uo, bo, Tt, outp);
}